// Round 9
// baseline (67.820 us; speedup 1.0000x reference)
//
#include <hip/hip_runtime.h>

// Slab-ocean 1D explicit Euler, parallel-in-time via ring-down truncation.
//   z = U + iV,  z_{n+1} = a*z_n + b_n,  a = (1 - dt*K1) + i*(-dt*fc) const.
// Hour-level: z_{k+1} = A z_k + S_k,  A = a^60,  S_k = cA*w_k + cB*w_{k+1}.
// |A| ~ 0.7: z_k = sum_m E_m w_m over the last NW=36 samples (exact k<=32,
// else truncation ~1e-5; absmax bit-identical to the exact scan since r5).
//   E_m: m==k -> cB;  m==0 -> A^{k-1} cA;  0<m<k -> A^{k-1-m} cC;  cC=cA+A*cB.
//
// r8 post-mortem: 72 KB LDS capped residency at 2 blocks/CU (8 waves/CU) --
// r3 showed store rate scales with waves -- and NT stores have never beaten
// ~5 TB/s while the harness fills do 6.9 TB/s with PLAIN dwordx4 stores at
// ~3 waves/CU (and the 165 MB output fits the 256 MB memory-side L3, which
// NT bypasses). This version:
//   - 36 KB LDS: stage ONE array per pass ([256 pts][36 smp] tile, 144-B
//     row stride = bank-optimal), 8 passes (4 tiles x {x,y}); accumulate
//     x/y contributions into per-tile z. Same global traffic as r8.
//     -> 4 blocks/CU LDS limit; all 672 blocks co-resident (10.5 waves/CU).
//   - PLAIN float4 stores (drop nontemporal), matching the fills' path.
//   - stage-2 forcing loads hoisted above stage 1 (latency hidden).
// Single plain launch, grid = 672 blocks (block = chunk k), 256 threads.

#define NT    40320
#define BPTS  1024
#define NF    672
#define NSUB  60
#define CH    60                 // steps per chunk = 1 forcing hour
#define NCH   (NT / CH)          // 672
#define PPT   4                  // points per thread in write -> float4 stores
#define NW    36                 // window samples (9 float4), >=32 transitions
#define NV    (NW / 4)           // 9 float4 vectors per row
#define TP    256                // points per staging tile
#define NTILE (BPTS / TP)        // 4 tiles

typedef float vf4 __attribute__((ext_vector_type(4)));

__global__ __launch_bounds__(256, 3)
void slab_chunk(const float* __restrict__ pk,
                const float* __restrict__ TAx,
                const float* __restrict__ TAy,
                const float* __restrict__ fcp,
                const int* __restrict__ dtp,
                float* __restrict__ out) {
    const int k   = blockIdx.x;           // chunk (hour) index
    const int tid = threadIdx.x;

    // ---- model coefficients ----
    const float dtf = (float)dtp[0];
    const float K0  = expf(pk[0]);
    const float K1  = expf(pk[1]);
    const float ar  = 1.0f - dtf * K1;    // Re(a)
    const float ai  = -dtf * fcp[0];      // Im(a)
    const float bs  = dtf * K0;           // forcing scale

    // ---- stage-2 forcing samples: issue EARLY, consume after stage 1 ----
    const int p0 = tid * PPT;
    const int f0 = k;
    const int f1 = (k + 1 < NF) ? k + 1 : NF - 1;
    float x0[PPT], x1[PPT], y0[PPT], y1[PPT];
#pragma unroll
    for (int j = 0; j < PPT; ++j) {
        const float* rx = TAx + (size_t)(p0 + j) * NF;
        const float* ry = TAy + (size_t)(p0 + j) * NF;
        x0[j] = rx[f0]; x1[j] = rx[f1];
        y0[j] = ry[f0]; y1[j] = ry[f1];
    }

    // g1 = sum a^m, g2 = sum ((59-m)/60) a^m, A = a^60  (one 60-iter pass)
    float g1r = 0.f, g1i = 0.f, g2r = 0.f, g2i = 0.f;
    float pr = 1.f, pi = 0.f;
    for (int m = 0; m < NSUB; ++m) {
        g1r += pr; g1i += pi;
        float w = (float)(NSUB - 1 - m) * (1.0f / NSUB);
        g2r = fmaf(w, pr, g2r); g2i = fmaf(w, pi, g2i);
        float nr = pr * ar - pi * ai;
        float ni = pr * ai + pi * ar;
        pr = nr; pi = ni;
    }
    const float Ar  = pr,        Ai  = pi;          // A = a^CH
    const float cAr = g1r - g2r, cAi = g1i - g2i;   // coeff of w_k     in S_k
    const float cBr = g2r,       cBi = g2i;         // coeff of w_{k+1} in S_k
    const float cCr = cAr + (Ar * cBr - Ai * cBi);  // cC = cA + A*cB
    const float cCi = cAi + (Ar * cBi + Ai * cBr);

    // ---- window geometry: samples [ja, ja+NW), 4-aligned; ja<0 for k<=31
    // (negative slots get zero weight; their loads clamp to offset 0) ----
    int va = (k + 4) & ~3;                // aligned exclusive end, va-1 >= k
    if (va > NF) va = NF;
    const int ja = va - NW;               // may be negative

    // ---- register weight table (fully unrolled -> stays in VGPRs) ----
    float wgtR[NW], wgtI[NW];
    {
        float Wr = 1.f, Wi = 0.f;         // tracks A^{k-1-m}; =1 at m=k-1
#pragma unroll
        for (int i = NW - 1; i >= 0; --i) {
            const int m = ja + i;
            float er = 0.f, ei = 0.f;
            if (k > 0 && m >= 0 && m <= k) {
                if (m == k) { er = cBr; ei = cBi; }
                else {
                    const float br = (m == 0) ? cAr : cCr;
                    const float bi = (m == 0) ? cAi : cCi;
                    er = Wr * br - Wi * bi;
                    ei = Wr * bi + Wi * br;
                    const float t2 = Wr * Ar - Wi * Ai;
                    Wi = Wr * Ai + Wi * Ar; Wr = t2;
                }
            }
            wgtR[i] = er; wgtI[i] = ei;
        }
    }

    // ---- stage 1: tile-staged coalesced window -> per-point z ----
    __shared__ float lds[TP][NW];         // 36 KB (one array at a time)
    float zr4[NTILE], zi4[NTILE];

#pragma unroll
    for (int tau = 0; tau < NTILE; ++tau) {
        float aR = 0.f, aI = 0.f;

        // ---- x pass ----
#pragma unroll
        for (int it = 0; it < NV; ++it) {
            const int V = tid + 256 * it;     // 0..2303 (256 rows x 9 vecs)
            const int r = V / NV;
            const int v = V - r * NV;
            int off = ja + 4 * v; if (off < 0) off = 0;   // clamp (zero-weight)
            *(vf4*)&lds[r][4 * v] =
                *(const vf4*)(TAx + (size_t)(tau * TP + r) * NF + off);
        }
        __syncthreads();
        {
            float dR = 0.f, dI = 0.f;
#pragma unroll
            for (int v = 0; v < NV; ++v) {
                const vf4 f = *(const vf4*)&lds[tid][4 * v];
#pragma unroll
                for (int e = 0; e < 4; ++e) {
                    const int i = 4 * v + e;
                    dR = fmaf(wgtR[i], f[e], dR);
                    dI = fmaf(wgtI[i], f[e], dI);
                }
            }
            aR += dR; aI += dI;               // (wR + i wI)(x) -> x-part
        }
        __syncthreads();

        // ---- y pass ----
#pragma unroll
        for (int it = 0; it < NV; ++it) {
            const int V = tid + 256 * it;
            const int r = V / NV;
            const int v = V - r * NV;
            int off = ja + 4 * v; if (off < 0) off = 0;
            *(vf4*)&lds[r][4 * v] =
                *(const vf4*)(TAy + (size_t)(tau * TP + r) * NF + off);
        }
        __syncthreads();
        {
            float dR = 0.f, dI = 0.f;
#pragma unroll
            for (int v = 0; v < NV; ++v) {
                const vf4 f = *(const vf4*)&lds[tid][4 * v];
#pragma unroll
                for (int e = 0; e < 4; ++e) {
                    const int i = 4 * v + e;
                    dR = fmaf(wgtR[i], f[e], dR);
                    dI = fmaf(wgtI[i], f[e], dI);
                }
            }
            aR -= dI; aI += dR;               // (wR + i wI)(i y) -> y-part
        }
        __syncthreads();

        zr4[tau] = bs * aR; zi4[tau] = bs * aI;
    }

    // ---- z-exchange: interleaved ownership -> consecutive p0=4*tid ----
    float2* zbuf = (float2*)&lds[0][0];   // 8 KB in dead tile LDS
#pragma unroll
    for (int tau = 0; tau < NTILE; ++tau)
        zbuf[tau * TP + tid] = make_float2(zr4[tau], zi4[tau]);
    __syncthreads();

    float zr[PPT], zi[PPT];
#pragma unroll
    for (int j = 0; j < PPT; ++j) {
        float2 z = zbuf[p0 + j];
        zr[j] = z.x; zi[j] = z.y;
    }

    // ---- stage 2: re-run chunk k exactly, stream U rows (r2-verified) ----
    float bx[PPT], by[PPT], dbx[PPT], dby[PPT];
#pragma unroll
    for (int j = 0; j < PPT; ++j) {
        bx[j]  = bs * x0[j];
        by[j]  = bs * y0[j];
        dbx[j] = bs * (x1[j] - x0[j]) * (1.0f / NSUB);
        dby[j] = bs * (y1[j] - y0[j]) * (1.0f / NSUB);
    }

    float* orow = out + (size_t)k * CH * BPTS + p0;

#pragma unroll 10
    for (int s = 0; s < CH; ++s) {
#pragma unroll
        for (int j = 0; j < PPT; ++j) {
            const float ur = fmaf(ar, zr[j], fmaf(-ai, zi[j], bx[j]));
            const float vi = fmaf(ar, zi[j], fmaf( ai, zr[j], by[j]));
            zr[j] = ur; zi[j] = vi;
            bx[j] += dbx[j]; by[j] += dby[j];
        }
        vf4 v; v.x = zr[0]; v.y = zr[1]; v.z = zr[2]; v.w = zr[3];
        *(vf4*)orow = v;                   // plain store: L2/L3 can absorb
        orow += BPTS;
    }
}

extern "C" void kernel_launch(void* const* d_in, const int* in_sizes, int n_in,
                              void* d_out, int out_size, void* d_ws, size_t ws_size,
                              hipStream_t stream) {
    const float* pk  = (const float*)d_in[0];
    const float* TAx = (const float*)d_in[1];
    const float* TAy = (const float*)d_in[2];
    const float* fcp = (const float*)d_in[3];
    const int*   dtp = (const int*)d_in[5];   // dt = 60
    float* out = (float*)d_out;

    slab_chunk<<<NCH, 256, 0, stream>>>(pk, TAx, TAy, fcp, dtp, out);
}

// Round 10
// 50.579 us; speedup vs baseline: 1.3409x; 1.3409x over previous
//
#include <hip/hip_runtime.h>

// Slab-ocean 1D explicit Euler, parallel-in-time via ring-down truncation.
//   z = U + iV,  z_{n+1} = a*z_n + b_n,  a = (1 - dt*K1) + i*(-dt*fc) const.
// Hour-level: z_{k+1} = A z_k + S_k,  A = a^60,  S_k = cA*w_k + cB*w_{k+1}.
// |A| <= ~0.67: z_k = sum_m E_m w_m over the last NW=32 samples (>=31
// transitions; truncation |A|^31*0.15 ~ 6e-7, 3 decades under the 4.88e-4
// fp32 noise floor every round has shown).
//   E_m: m==k -> cB;  m==0 -> A^{k-1} cA;  0<m<k -> A^{k-1-m} cC;  cC=cA+A*cB.
//
// r9 post-mortem: plain stores REGRESSED (56.4 -> 67.8) -- the write stream
// must stay out of the cache path (NT) or it thrashes against staging reads.
// This version = r8's proven config (combined 72KB staging, NT float4
// stores) + two changes:
//   1) XCD-AWARE SWIZZLE: k = (bid&7)*84 + bid>>3. Stage 1 re-reads ~190 MB
//      of forcing chip-wide; unique data (5.5 MB) > one XCD L2 (4 MB) under
//      round-robin dispatch -> L3 served it, contending with the 165 MB NT
//      write stream. With a contiguous 84-chunk k-range per XCD the per-XCD
//      working set is (84+36)*1024*2*4 B ~ 0.98 MB -> L2-resident re-reads
//      (34.5 TB/s aggregate), write stream decontended.
//   2) window data 36 -> 32 samples (8 float4/row); LDS keeps the 36-float
//      row stride (bank-optimal padding, b128 reads at structural minimum).
// Single plain launch, grid = 672 blocks (block = chunk k), 256 threads.

#define NT    40320
#define BPTS  1024
#define NF    672
#define NSUB  60
#define CH    60                 // steps per chunk = 1 forcing hour
#define NCH   (NT / CH)          // 672
#define PPT   4                  // points per thread in write -> float4 stores
#define NW    32                 // window samples loaded (8 float4)
#define NV    (NW / 4)           // 8 float4 vectors per row
#define LSTR  36                 // LDS row stride in floats (bank-optimal pad)
#define TP    256                // points per staging tile
#define NTILE (BPTS / TP)        // 4 tiles
#define NXCD  8

typedef float vf4 __attribute__((ext_vector_type(4)));

__global__ __launch_bounds__(256, 2)
void slab_chunk(const float* __restrict__ pk,
                const float* __restrict__ TAx,
                const float* __restrict__ TAy,
                const float* __restrict__ fcp,
                const int* __restrict__ dtp,
                float* __restrict__ out) {
    // XCD-aware swizzle: contiguous k-range of 84 chunks per XCD.
    const int bid = blockIdx.x;
    const int k   = (bid & (NXCD - 1)) * (NCH / NXCD) + (bid >> 3);
    const int tid = threadIdx.x;

    // ---- model coefficients ----
    const float dtf = (float)dtp[0];
    const float K0  = expf(pk[0]);
    const float K1  = expf(pk[1]);
    const float ar  = 1.0f - dtf * K1;    // Re(a)
    const float ai  = -dtf * fcp[0];      // Im(a)
    const float bs  = dtf * K0;           // forcing scale

    // g1 = sum a^m, g2 = sum ((59-m)/60) a^m, A = a^60  (one 60-iter pass)
    float g1r = 0.f, g1i = 0.f, g2r = 0.f, g2i = 0.f;
    float pr = 1.f, pi = 0.f;
    for (int m = 0; m < NSUB; ++m) {
        g1r += pr; g1i += pi;
        float w = (float)(NSUB - 1 - m) * (1.0f / NSUB);
        g2r = fmaf(w, pr, g2r); g2i = fmaf(w, pi, g2i);
        float nr = pr * ar - pi * ai;
        float ni = pr * ai + pi * ar;
        pr = nr; pi = ni;
    }
    const float Ar  = pr,        Ai  = pi;          // A = a^CH
    const float cAr = g1r - g2r, cAi = g1i - g2i;   // coeff of w_k     in S_k
    const float cBr = g2r,       cBi = g2i;         // coeff of w_{k+1} in S_k
    const float cCr = cAr + (Ar * cBr - Ai * cBi);  // cC = cA + A*cB
    const float cCi = cAi + (Ar * cBi + Ai * cBr);

    // ---- window geometry: samples [ja, ja+NW), 4-aligned; ja<0 for small k
    // (negative slots get zero weight; their loads clamp to offset 0) ----
    int va = (k + 4) & ~3;                // aligned exclusive end, va-1 >= k
    if (va > NF) va = NF;
    const int ja = va - NW;               // may be negative

    // ---- register weight table (fully unrolled -> stays in VGPRs) ----
    float wgtR[NW], wgtI[NW];
    {
        float Wr = 1.f, Wi = 0.f;         // tracks A^{k-1-m}; =1 at m=k-1
#pragma unroll
        for (int i = NW - 1; i >= 0; --i) {
            const int m = ja + i;
            float er = 0.f, ei = 0.f;
            if (k > 0 && m >= 0 && m <= k) {
                if (m == k) { er = cBr; ei = cBi; }
                else {
                    const float br = (m == 0) ? cAr : cCr;
                    const float bi = (m == 0) ? cAi : cCi;
                    er = Wr * br - Wi * bi;
                    ei = Wr * bi + Wi * br;
                    const float t2 = Wr * Ar - Wi * Ai;
                    Wi = Wr * Ai + Wi * Ar; Wr = t2;
                }
            }
            wgtR[i] = er; wgtI[i] = ei;
        }
    }

    // ---- stage 1: tile-staged coalesced window -> per-point z ----
    __shared__ float ldsx[TP][LSTR];      // 36.9 KB (rows padded to 36 floats)
    __shared__ float ldsy[TP][LSTR];      // 36.9 KB
    float zr4[NTILE], zi4[NTILE];

#pragma unroll
    for (int tau = 0; tau < NTILE; ++tau) {
        // load tile tau: V -> (row=V/8, vec=V%8); lanes walk vf4s within rows
#pragma unroll
        for (int it = 0; it < NV; ++it) {
            const int V = tid + 256 * it;     // 0..2047 (256 rows x 8 vecs)
            const int r = V >> 3;
            const int v = V & 7;
            int off = ja + 4 * v; if (off < 0) off = 0;   // clamp (zero-weight)
            const size_t gbase = (size_t)(tau * TP + r) * NF + off;
            *(vf4*)&ldsx[r][4 * v] = *(const vf4*)(TAx + gbase);
            *(vf4*)&ldsy[r][4 * v] = *(const vf4*)(TAy + gbase);
        }
        __syncthreads();

        // consume: thread t owns point tau*TP + t (row t of the tile)
        float aR = 0.f, aI = 0.f;
#pragma unroll
        for (int v = 0; v < NV; ++v) {
            const vf4 fx = *(const vf4*)&ldsx[tid][4 * v];
            const vf4 fy = *(const vf4*)&ldsy[tid][4 * v];
#pragma unroll
            for (int e = 0; e < 4; ++e) {
                const int i = 4 * v + e;
                aR = fmaf(wgtR[i], fx[e], fmaf(-wgtI[i], fy[e], aR));
                aI = fmaf(wgtR[i], fy[e], fmaf( wgtI[i], fx[e], aI));
            }
        }
        zr4[tau] = bs * aR; zi4[tau] = bs * aI;
        __syncthreads();                  // before next tile overwrites LDS
    }

    // ---- z-exchange: interleaved ownership -> consecutive p0=4*tid ----
    float2* zbuf = (float2*)&ldsx[0][0];  // 8 KB in dead tile LDS
#pragma unroll
    for (int tau = 0; tau < NTILE; ++tau)
        zbuf[tau * TP + tid] = make_float2(zr4[tau], zi4[tau]);
    __syncthreads();

    const int p0 = tid * PPT;
    float zr[PPT], zi[PPT];
#pragma unroll
    for (int j = 0; j < PPT; ++j) {
        float2 z = zbuf[p0 + j];
        zr[j] = z.x; zi[j] = z.y;
    }

    // ---- stage 2: re-run chunk k exactly, stream U rows (r2-verified) ----
    const int f0 = k;
    const int f1 = (k + 1 < NF) ? k + 1 : NF - 1;

    float bx[PPT], by[PPT], dbx[PPT], dby[PPT];
#pragma unroll
    for (int j = 0; j < PPT; ++j) {
        const float* rx = TAx + (size_t)(p0 + j) * NF;
        const float* ry = TAy + (size_t)(p0 + j) * NF;
        const float x0 = rx[f0], x1 = rx[f1];
        const float y0 = ry[f0], y1 = ry[f1];
        bx[j]  = bs * x0;
        by[j]  = bs * y0;
        dbx[j] = bs * (x1 - x0) * (1.0f / NSUB);
        dby[j] = bs * (y1 - y0) * (1.0f / NSUB);
    }

    float* orow = out + (size_t)k * CH * BPTS + p0;

#pragma unroll 10
    for (int s = 0; s < CH; ++s) {
#pragma unroll
        for (int j = 0; j < PPT; ++j) {
            const float ur = fmaf(ar, zr[j], fmaf(-ai, zi[j], bx[j]));
            const float vi = fmaf(ar, zi[j], fmaf( ai, zr[j], by[j]));
            zr[j] = ur; zi[j] = vi;
            bx[j] += dbx[j]; by[j] += dby[j];
        }
        vf4 v; v.x = zr[0]; v.y = zr[1]; v.z = zr[2]; v.w = zr[3];
        __builtin_nontemporal_store(v, (vf4*)orow);
        orow += BPTS;
    }
}

extern "C" void kernel_launch(void* const* d_in, const int* in_sizes, int n_in,
                              void* d_out, int out_size, void* d_ws, size_t ws_size,
                              hipStream_t stream) {
    const float* pk  = (const float*)d_in[0];
    const float* TAx = (const float*)d_in[1];
    const float* TAy = (const float*)d_in[2];
    const float* fcp = (const float*)d_in[3];
    const int*   dtp = (const int*)d_in[5];   // dt = 60
    float* out = (float*)d_out;

    slab_chunk<<<NCH, 256, 0, stream>>>(pk, TAx, TAy, fcp, dtp, out);
}